// Round 19
// baseline (506.932 us; speedup 1.0000x reference)
//
#include <hip/hip_runtime.h>
#include <hip/hip_bf16.h>

#define HD 64

typedef unsigned short u16;

__device__ __forceinline__ float lrelu(float x) { return x > 0.f ? x : 0.2f * x; }
__device__ __forceinline__ int clampi(int v, int maxv) {
    return v < 0 ? 0 : (v >= maxv ? maxv - 1 : v);
}
__device__ __forceinline__ float bf2f(u16 u) {
    return __uint_as_float(((unsigned int)u) << 16);
}
// round-to-nearest-even fp32 -> bf16 (bit-level; inputs are finite)
__device__ __forceinline__ u16 f2bf(float f) {
    unsigned int u = __float_as_uint(f);
    unsigned int lsb = (u >> 16) & 1u;
    u += 0x7fffu + lsb;
    return (u16)(u >> 16);
}

// ---------------- init + node_emb fused ----------------
__global__ void k_init_emb(const float* __restrict__ x, const float* __restrict__ W,
                           const float* __restrict__ b, float* __restrict__ h,
                           int* deg, int* cursor, int* gcnt, float* pooled,
                           int N, int B) {
    int i = blockIdx.x * blockDim.x + threadIdx.x;
    if (i < N) { deg[i] = 0; cursor[i] = 0; }
    if (i < B) gcnt[i] = 0;
    if (i < B * HD) pooled[i] = 0.f;
    if (i < N * HD) {
        int n = i >> 6, c = i & 63;
        float acc = b[c];
        acc = fmaf(x[n * 3 + 0], W[0 * HD + c], acc);
        acc = fmaf(x[n * 3 + 1], W[1 * HD + c], acc);
        acc = fmaf(x[n * 3 + 2], W[2 * HD + c], acc);
        h[i] = fmaxf(acc, 0.f);
    }
}

// ---------------- degree histogram + graph-count LDS histogram fused ----------------
#define MAXB 2048
__global__ void k_deg_gse(const int* __restrict__ dst, int* __restrict__ deg,
                          const int* __restrict__ batch, int* __restrict__ gcnt,
                          int E, int N, int B) {
    __shared__ int s_cnt[MAXB];
    int t = threadIdx.x;
    int Bc = B < MAXB ? B : MAXB;
    for (int i = t; i < Bc; i += blockDim.x) s_cnt[i] = 0;
    __syncthreads();
    int gid = blockIdx.x * blockDim.x + t;
    if (gid < E) atomicAdd(&deg[clampi(dst[gid], N)], 1);
    if (gid < N) {
        int b = clampi(batch[gid], B);
        if (b < MAXB) atomicAdd(&s_cnt[b], 1);
        else atomicAdd(&gcnt[b], 1);
    }
    __syncthreads();
    for (int i = t; i < Bc; i += blockDim.x)
        if (s_cnt[i] != 0) atomicAdd(&gcnt[i], s_cnt[i]);
}

// ---------------- hierarchical scan ----------------
__global__ void k_scan1(const int* __restrict__ deg, int* __restrict__ tmp,
                        int* __restrict__ bsum, int N) {
    __shared__ int s[256];
    int tid = threadIdx.x;
    int i = blockIdx.x * 256 + tid;
    int v = (i < N) ? deg[i] : 0;
    s[tid] = v;
    __syncthreads();
    for (int off = 1; off < 256; off <<= 1) {
        int t = (tid >= off) ? s[tid - off] : 0;
        __syncthreads();
        s[tid] += t;
        __syncthreads();
    }
    if (i < N) tmp[i] = s[tid];
    if (tid == 255) bsum[blockIdx.x] = s[255];
}
__global__ void k_scan2(const int* __restrict__ bsum, int* __restrict__ boff, int nb) {
    __shared__ int s[1024];
    int tid = threadIdx.x;
    int v = (tid < nb) ? bsum[tid] : 0;
    s[tid] = v;
    __syncthreads();
    for (int off = 1; off < 1024; off <<= 1) {
        int t = (tid >= off) ? s[tid - off] : 0;
        __syncthreads();
        s[tid] += t;
        __syncthreads();
    }
    if (tid < nb) boff[tid] = s[tid] - v;   // exclusive
}
__global__ void k_scan3(const int* __restrict__ tmp, const int* __restrict__ boff,
                        int* __restrict__ row_ptr, int N) {
    int i = blockIdx.x * blockDim.x + threadIdx.x;
    if (i == 0) row_ptr[0] = 0;
    if (i < N) row_ptr[i + 1] = tmp[i] + boff[i >> 8];
}

// ---------------- CSR scatter ----------------
__global__ void k_csr(const int* __restrict__ src, const int* __restrict__ dst,
                      const int* __restrict__ row_ptr, int* __restrict__ cursor,
                      int* __restrict__ csr_src, int* __restrict__ csr_dst,
                      int* __restrict__ csr_eid, int E, int N) {
    int e = blockIdx.x * blockDim.x + threadIdx.x;
    if (e >= E) return;
    int d = clampi(dst[e], N);
    int pos = row_ptr[d] + atomicAdd(&cursor[d], 1);
    if (pos < E) {
        csr_src[pos] = clampi(src[e], N);
        csr_dst[pos] = d;
        csr_eid[pos] = e;
    }
}

// ---------------- ONCE: a_ed all 3 layers x 4 heads, CSR order, 4 edges/thread ----
__global__ __launch_bounds__(256) void k_ee(
    const float* __restrict__ edge_attr, const float* __restrict__ eW,
    const float* __restrict__ eB, const float* __restrict__ lin_eW,
    const float* __restrict__ att_e, const int* __restrict__ csr_eid,
    float* __restrict__ aed, int E) {
    __shared__ float s_ew[256];
    __shared__ float s_eb[64];
    __shared__ float s_wred[768];  // [l*256 + h*64 + d]
    int t = threadIdx.x;
    s_ew[t] = eW[t];
    if (t < 64) s_eb[t] = eB[t];
    for (int idx = t; idx < 768; idx += 256) {
        int l = idx >> 8, hd = idx & 255, hh = hd >> 6, d = hd & 63;
        const float* We = lin_eW + (size_t)l * HD * 256;
        const float* ae = att_e + (size_t)l * 256;
        float acc = 0.f;
        for (int c = 0; c < 64; c++)
            acc = fmaf(We[d * 256 + hh * 64 + c], ae[hh * 64 + c], acc);
        s_wred[idx] = acc;
    }
    __syncthreads();
    int j0 = (blockIdx.x * 256 + t) * 4;
    if (j0 >= E) return;
    float4 a[4];
    int nv = 0;
    #pragma unroll
    for (int q = 0; q < 4; q++) {
        int j = j0 + q;
        if (j < E) {
            a[q] = *(const float4*)(edge_attr + (size_t)csr_eid[j] * 4);
            nv = q + 1;
        } else {
            a[q] = make_float4(0.f, 0.f, 0.f, 0.f);
        }
    }
    float acc[4][12];
    #pragma unroll
    for (int q = 0; q < 4; q++)
        #pragma unroll
        for (int m = 0; m < 12; m++) acc[q][m] = 0.f;
    for (int k = 0; k < HD; k++) {
        float e0 = s_ew[k], e1 = s_ew[64 + k], e2 = s_ew[128 + k], e3 = s_ew[192 + k];
        float eb = s_eb[k];
        float w[12];
        #pragma unroll
        for (int m = 0; m < 12; m++)
            w[m] = s_wred[(m >> 2) * 256 + (m & 3) * 64 + k];
        #pragma unroll
        for (int q = 0; q < 4; q++) {
            float v = fmaf(a[q].x, e0, fmaf(a[q].y, e1,
                      fmaf(a[q].z, e2, fmaf(a[q].w, e3, eb))));
            v = fmaxf(v, 0.f);
            #pragma unroll
            for (int m = 0; m < 12; m++) acc[q][m] = fmaf(v, w[m], acc[q][m]);
        }
    }
    #pragma unroll
    for (int q = 0; q < 4; q++) {
        if (q >= nv) break;
        float* o = aed + (size_t)(j0 + q) * 12;
        #pragma unroll
        for (int m = 0; m < 12; m++) o[m] = acc[q][m];
    }
}

// ---------------- ONCE: self-loop a_ed rows by LINEARITY ----------------
__global__ void k_selfed(const int* __restrict__ row_ptr, float* __restrict__ aed,
                         int E, int N) {
    int n = blockIdx.x * blockDim.x + threadIdx.x;
    if (n >= N) return;
    int r0 = row_ptr[n], r1 = row_ptr[n + 1];
    float acc[12];
    #pragma unroll
    for (int m = 0; m < 12; m++) acc[m] = 0.f;
    for (int j = r0; j < r1; j++) {
        const float* p = aed + (size_t)j * 12;
        #pragma unroll
        for (int m = 0; m < 12; m++) acc[m] += p[m];
    }
    float inv = 1.f / fmaxf((float)(r1 - r0), 1.f);
    float* o = aed + (size_t)(E + n) * 12;
    #pragma unroll
    for (int m = 0; m < 12; m++) o[m] = acc[m] * inv;
}

// ---------------- per-layer: xp = h@W, 8 nodes per block ----------------
__global__ __launch_bounds__(256) void k_xp(
    const float* __restrict__ h, const float* __restrict__ W,
    const float* __restrict__ asrc, const float* __restrict__ adst,
    u16* __restrict__ xp, float* __restrict__ a_s, float* __restrict__ a_d, int N) {
    __shared__ float hs[8 * HD];
    int n0 = blockIdx.x * 8;
    int t = threadIdx.x;
    for (int i = t; i < 8 * HD; i += 256) {
        int nn = n0 + (i >> 6);
        hs[i] = (nn < N) ? h[(size_t)nn * HD + (i & 63)] : 0.f;
    }
    __syncthreads();
    int c = t;
    float acc[8];
    #pragma unroll
    for (int k = 0; k < 8; k++) acc[k] = 0.f;
    for (int d = 0; d < HD; d++) {
        float wv = W[d * 256 + c];
        #pragma unroll
        for (int k = 0; k < 8; k++) acc[k] = fmaf(hs[k * HD + d], wv, acc[k]);
    }
    float as_ = asrc[c], ad_ = adst[c];
    int hh = c >> 6, cc = c & 63;
    #pragma unroll
    for (int k = 0; k < 8; k++) {
        int nn = n0 + k;
        float ps = acc[k] * as_;
        float pd = acc[k] * ad_;
        #pragma unroll
        for (int o = 32; o > 0; o >>= 1) {
            ps += __shfl_xor(ps, o);
            pd += __shfl_xor(pd, o);
        }
        if (nn < N) {
            xp[(size_t)nn * 256 + c] = f2bf(acc[k]);
            if (cc == 0) { a_s[nn * 4 + hh] = ps; a_d[nn * 4 + hh] = pd; }
        }
    }
}

// ---------------- per-layer: attention weights (lite, coalesced write) ----------------
__global__ void k_w(const int* __restrict__ csr_src, const int* __restrict__ csr_dst,
                    const float* __restrict__ aed, const float* __restrict__ a_s,
                    const float* __restrict__ a_d, float* __restrict__ wcsr,
                    int layer, int E, int N) {
    int j = blockIdx.x * blockDim.x + threadIdx.x;
    if (j >= E + N) return;
    int s, d;
    if (j < E) { s = csr_src[j]; d = csr_dst[j]; }
    else       { s = j - E; d = s; }
    const float* p = aed + (size_t)j * 12 + layer * 4;
    float4 as4 = *(const float4*)(a_s + s * 4);
    float4 ad4 = *(const float4*)(a_d + d * 4);
    float w0 = __expf(lrelu(as4.x + ad4.x + p[0]));
    float w1 = __expf(lrelu(as4.y + ad4.y + p[1]));
    float w2 = __expf(lrelu(as4.z + ad4.z + p[2]));
    float w3 = __expf(lrelu(as4.w + ad4.w + p[3]));
    *(float4*)(wcsr + (size_t)j * 4) = make_float4(w0, w1, w2, w3);
}

// ---------------- per-layer GAT aggregate: edge-parallel within wave ----------------
// Sequential wcsr stream (precomputed weights — keeps the gather loop's body
// free of dependent loads; R18's inline-w fusion regressed 412->501 us).
// Last layer pools directly via atomics.
__global__ __launch_bounds__(256) void k_gat(
    const u16* __restrict__ xp, const float* __restrict__ wcsr,
    const int* __restrict__ row_ptr, const int* __restrict__ csr_src,
    const float* __restrict__ convb, const int* __restrict__ batch,
    float* __restrict__ pooled, int do_pool, float* __restrict__ h_out,
    int N, int E, int B) {
    int wave = threadIdx.x >> 6, lane = threadIdx.x & 63;
    int n = blockIdx.x * 4 + wave;
    if (n >= N) return;
    int g = lane >> 4, p = lane & 15;
    int r0 = row_ptr[n], r1 = row_ptr[n + 1];
    float a00 = 0.f, a01 = 0.f, a02 = 0.f, a03 = 0.f;
    float a10 = 0.f, a11 = 0.f, a12 = 0.f, a13 = 0.f;
    float a20 = 0.f, a21 = 0.f, a22 = 0.f, a23 = 0.f;
    float a30 = 0.f, a31 = 0.f, a32 = 0.f, a33 = 0.f;
    float d0 = 0.f, d1 = 0.f, d2 = 0.f, d3 = 0.f;
    if (g == 0) {
        float4 w = *(const float4*)(wcsr + (size_t)(E + n) * 4);
        const u16* row = xp + (size_t)n * 256 + p * 4;
        ushort4 v0 = *(const ushort4*)(row);
        ushort4 v1 = *(const ushort4*)(row + 64);
        ushort4 v2 = *(const ushort4*)(row + 128);
        ushort4 v3 = *(const ushort4*)(row + 192);
        d0 += w.x; d1 += w.y; d2 += w.z; d3 += w.w;
        a00 = fmaf(w.x, bf2f(v0.x), a00); a01 = fmaf(w.x, bf2f(v0.y), a01);
        a02 = fmaf(w.x, bf2f(v0.z), a02); a03 = fmaf(w.x, bf2f(v0.w), a03);
        a10 = fmaf(w.y, bf2f(v1.x), a10); a11 = fmaf(w.y, bf2f(v1.y), a11);
        a12 = fmaf(w.y, bf2f(v1.z), a12); a13 = fmaf(w.y, bf2f(v1.w), a13);
        a20 = fmaf(w.z, bf2f(v2.x), a20); a21 = fmaf(w.z, bf2f(v2.y), a21);
        a22 = fmaf(w.z, bf2f(v2.z), a22); a23 = fmaf(w.z, bf2f(v2.w), a23);
        a30 = fmaf(w.w, bf2f(v3.x), a30); a31 = fmaf(w.w, bf2f(v3.y), a31);
        a32 = fmaf(w.w, bf2f(v3.z), a32); a33 = fmaf(w.w, bf2f(v3.w), a33);
    }
    for (int j = r0 + g; j < r1; j += 4) {
        float4 w = *(const float4*)(wcsr + (size_t)j * 4);
        const u16* row = xp + (size_t)csr_src[j] * 256 + p * 4;
        ushort4 v0 = *(const ushort4*)(row);
        ushort4 v1 = *(const ushort4*)(row + 64);
        ushort4 v2 = *(const ushort4*)(row + 128);
        ushort4 v3 = *(const ushort4*)(row + 192);
        d0 += w.x; d1 += w.y; d2 += w.z; d3 += w.w;
        a00 = fmaf(w.x, bf2f(v0.x), a00); a01 = fmaf(w.x, bf2f(v0.y), a01);
        a02 = fmaf(w.x, bf2f(v0.z), a02); a03 = fmaf(w.x, bf2f(v0.w), a03);
        a10 = fmaf(w.y, bf2f(v1.x), a10); a11 = fmaf(w.y, bf2f(v1.y), a11);
        a12 = fmaf(w.y, bf2f(v1.z), a12); a13 = fmaf(w.y, bf2f(v1.w), a13);
        a20 = fmaf(w.z, bf2f(v2.x), a20); a21 = fmaf(w.z, bf2f(v2.y), a21);
        a22 = fmaf(w.z, bf2f(v2.z), a22); a23 = fmaf(w.z, bf2f(v2.w), a23);
        a30 = fmaf(w.w, bf2f(v3.x), a30); a31 = fmaf(w.w, bf2f(v3.y), a31);
        a32 = fmaf(w.w, bf2f(v3.z), a32); a33 = fmaf(w.w, bf2f(v3.w), a33);
    }
    d0 += __shfl_xor(d0, 16); d0 += __shfl_xor(d0, 32);
    d1 += __shfl_xor(d1, 16); d1 += __shfl_xor(d1, 32);
    d2 += __shfl_xor(d2, 16); d2 += __shfl_xor(d2, 32);
    d3 += __shfl_xor(d3, 16); d3 += __shfl_xor(d3, 32);
    float i0 = 1.f / d0, i1 = 1.f / d1, i2 = 1.f / d2, i3 = 1.f / d3;
    float m0 = a00 * i0 + a10 * i1 + a20 * i2 + a30 * i3;
    float m1 = a01 * i0 + a11 * i1 + a21 * i2 + a31 * i3;
    float m2 = a02 * i0 + a12 * i1 + a22 * i2 + a32 * i3;
    float m3 = a03 * i0 + a13 * i1 + a23 * i2 + a33 * i3;
    m0 += __shfl_xor(m0, 16); m0 += __shfl_xor(m0, 32);
    m1 += __shfl_xor(m1, 16); m1 += __shfl_xor(m1, 32);
    m2 += __shfl_xor(m2, 16); m2 += __shfl_xor(m2, 32);
    m3 += __shfl_xor(m3, 16); m3 += __shfl_xor(m3, 32);
    if (lane < 16) {
        int c = p * 4;
        float o0 = fmaxf(0.25f * m0 + convb[c + 0], 0.f);
        float o1 = fmaxf(0.25f * m1 + convb[c + 1], 0.f);
        float o2 = fmaxf(0.25f * m2 + convb[c + 2], 0.f);
        float o3 = fmaxf(0.25f * m3 + convb[c + 3], 0.f);
        if (do_pool) {
            int b = clampi(batch[n], B);
            atomicAdd(&pooled[b * HD + c + 0], o0);
            atomicAdd(&pooled[b * HD + c + 1], o1);
            atomicAdd(&pooled[b * HD + c + 2], o2);
            atomicAdd(&pooled[b * HD + c + 3], o3);
        } else {
            h_out[(size_t)n * HD + c + 0] = o0;
            h_out[(size_t)n * HD + c + 1] = o1;
            h_out[(size_t)n * HD + c + 2] = o2;
            h_out[(size_t)n * HD + c + 3] = o3;
        }
    }
}

// ---------------- final MLP (fp32 out; divides pooled sum by count) ----------------
__global__ void k_mlp(const float* __restrict__ u, const float* __restrict__ gW,
                      const float* __restrict__ gb, const float* __restrict__ pooled,
                      const int* __restrict__ gcnt, const float* __restrict__ f1W,
                      const float* __restrict__ f1b, const float* __restrict__ f2W,
                      const float* __restrict__ f2b, float* __restrict__ out, int B) {
    __shared__ float z[2 * HD];
    __shared__ float z1s[HD];
    int b = blockIdx.x, t = threadIdx.x;  // 64 threads
    float acc = gb[t];
    for (int k = 0; k < 10; k++) acc = fmaf(u[b * 10 + k], gW[k * HD + t], acc);
    z[HD + t] = fmaxf(acc, 0.f);
    float invc = 1.f / fmaxf((float)gcnt[b], 1.f);
    z[t] = pooled[b * HD + t] * invc;
    __syncthreads();
    float a1 = f1b[t];
    for (int k = 0; k < 2 * HD; k++) a1 = fmaf(z[k], f1W[k * HD + t], a1);
    z1s[t] = fmaxf(a1, 0.f);
    __syncthreads();
    if (t < 2) {
        float o = f2b[t];
        for (int k = 0; k < HD; k++) o = fmaf(z1s[k], f2W[k * 2 + t], o);
        out[b * 2 + t] = o;
    }
}

extern "C" void kernel_launch(void* const* d_in, const int* in_sizes, int n_in,
                              void* d_out, int out_size, void* d_ws, size_t ws_size,
                              hipStream_t stream) {
    const float* x         = (const float*)d_in[0];
    const int*   ei        = (const int*)d_in[1];
    const float* edge_attr = (const float*)d_in[2];
    const float* u         = (const float*)d_in[3];
    const int*   batch     = (const int*)d_in[4];
    const float* node_W    = (const float*)d_in[5];
    const float* node_b    = (const float*)d_in[6];
    const float* eemb_W    = (const float*)d_in[7];
    const float* eemb_b    = (const float*)d_in[8];
    const float* lin_W     = (const float*)d_in[9];
    const float* att_src   = (const float*)d_in[10];
    const float* att_dst   = (const float*)d_in[11];
    const float* lin_eW    = (const float*)d_in[12];
    const float* att_e     = (const float*)d_in[13];
    const float* conv_b    = (const float*)d_in[14];
    const float* gW        = (const float*)d_in[15];
    const float* gb        = (const float*)d_in[16];
    const float* f1W       = (const float*)d_in[17];
    const float* f1b       = (const float*)d_in[18];
    const float* f2W       = (const float*)d_in[19];
    const float* f2b       = (const float*)d_in[20];

    const int N = in_sizes[0] / 3;
    const int E = in_sizes[2] / 4;
    const int B = in_sizes[3] / 10;
    const int* src = ei;
    const int* dst = ei + E;
    const int NB = (N + 255) / 256;
    const int MEN = (E > N ? E : N);

    // workspace carve (fp32 then bf16 then ints)
    float* wsf = (float*)d_ws;
    float* h       = wsf;              wsf += (size_t)N * HD;
    float* a_s     = wsf;              wsf += (size_t)N * 4;
    float* a_d     = wsf;              wsf += (size_t)N * 4;
    float* aed     = wsf;              wsf += (size_t)(E + N) * 12;
    float* wcsr    = wsf;              wsf += (size_t)(E + N) * 4;
    float* pooled  = wsf;              wsf += (size_t)B * HD;
    u16* xp = (u16*)wsf;               wsf += (size_t)N * 128;   // N*256 bf16
    int* wsi = (int*)wsf;
    int* deg     = wsi;                wsi += N;
    int* row_ptr = wsi;                wsi += N + 1;
    int* cursor  = wsi;                wsi += N;
    int* tmp     = wsi;                wsi += N;
    int* bsum    = wsi;                wsi += NB + 1;
    int* boff    = wsi;                wsi += NB + 1;
    int* csr_src = wsi;                wsi += E;
    int* csr_dst = wsi;                wsi += E;
    int* csr_eid = wsi;                wsi += E;
    int* gcnt    = wsi;                wsi += B;

    k_init_emb<<<(N * HD + 255) / 256, 256, 0, stream>>>(x, node_W, node_b, h,
                                                         deg, cursor, gcnt, pooled, N, B);
    k_deg_gse<<<(MEN + 255) / 256, 256, 0, stream>>>(dst, deg, batch, gcnt, E, N, B);
    k_scan1<<<NB, 256, 0, stream>>>(deg, tmp, bsum, N);
    k_scan2<<<1, 1024, 0, stream>>>(bsum, boff, NB);
    k_scan3<<<NB, 256, 0, stream>>>(tmp, boff, row_ptr, N);
    k_csr<<<(E + 255) / 256, 256, 0, stream>>>(src, dst, row_ptr, cursor,
                                               csr_src, csr_dst, csr_eid, E, N);
    k_ee<<<(E + 1023) / 1024, 256, 0, stream>>>(edge_attr, eemb_W, eemb_b, lin_eW, att_e,
                                                csr_eid, aed, E);
    k_selfed<<<NB, 256, 0, stream>>>(row_ptr, aed, E, N);
    for (int i = 0; i < 3; i++) {
        k_xp<<<(N + 7) / 8, 256, 0, stream>>>(h, lin_W + (size_t)i * HD * 256,
                                              att_src + (size_t)i * 256,
                                              att_dst + (size_t)i * 256,
                                              xp, a_s, a_d, N);
        k_w<<<(E + N + 255) / 256, 256, 0, stream>>>(csr_src, csr_dst, aed, a_s, a_d,
                                                     wcsr, i, E, N);
        k_gat<<<(N + 3) / 4, 256, 0, stream>>>(xp, wcsr, row_ptr, csr_src,
                                               conv_b + (size_t)i * HD, batch, pooled,
                                               (i == 2) ? 1 : 0, h, N, E, B);
    }
    k_mlp<<<B, 64, 0, stream>>>(u, gW, gb, pooled, gcnt, f1W, f1b, f2W, f2b,
                                (float*)d_out, B);
}

// Round 20
// 414.791 us; speedup vs baseline: 1.2221x; 1.2221x over previous
//
#include <hip/hip_runtime.h>
#include <hip/hip_bf16.h>

#define HD 64

typedef unsigned short u16;

__device__ __forceinline__ float lrelu(float x) { return x > 0.f ? x : 0.2f * x; }
__device__ __forceinline__ int clampi(int v, int maxv) {
    return v < 0 ? 0 : (v >= maxv ? maxv - 1 : v);
}
__device__ __forceinline__ float bf2f(u16 u) {
    return __uint_as_float(((unsigned int)u) << 16);
}
// round-to-nearest-even fp32 -> bf16 (bit-level; inputs are finite)
__device__ __forceinline__ u16 f2bf(float f) {
    unsigned int u = __float_as_uint(f);
    unsigned int lsb = (u >> 16) & 1u;
    u += 0x7fffu + lsb;
    return (u16)(u >> 16);
}

// ---------------- init: zero deg/cursor/pooled/gcnt ----------------
__global__ void k_init(int* deg, int* cursor, int* gcnt, float* pooled, int N, int B) {
    int i = blockIdx.x * blockDim.x + threadIdx.x;
    if (i < N) { deg[i] = 0; cursor[i] = 0; }
    if (i < B) gcnt[i] = 0;
    if (i < B * HD) pooled[i] = 0.f;
}

// ---------------- h = relu(x @ node_W + node_b),  x:[N,3] W:[3,64] ----------------
__global__ void k_node_emb(const float* __restrict__ x, const float* __restrict__ W,
                           const float* __restrict__ b, float* __restrict__ h, int N) {
    int i = blockIdx.x * blockDim.x + threadIdx.x;
    if (i >= N * HD) return;
    int n = i >> 6, c = i & 63;
    float acc = b[c];
    acc = fmaf(x[n * 3 + 0], W[0 * HD + c], acc);
    acc = fmaf(x[n * 3 + 1], W[1 * HD + c], acc);
    acc = fmaf(x[n * 3 + 2], W[2 * HD + c], acc);
    h[i] = fmaxf(acc, 0.f);
}

// ---------------- degree histogram over dst ----------------
__global__ void k_deg(const int* __restrict__ dst, int* __restrict__ deg, int E, int N) {
    int e = blockIdx.x * blockDim.x + threadIdx.x;
    if (e < E) atomicAdd(&deg[clampi(dst[e], N)], 1);
}

// ---------------- hierarchical scan ----------------
__global__ void k_scan1(const int* __restrict__ deg, int* __restrict__ tmp,
                        int* __restrict__ bsum, int N) {
    __shared__ int s[256];
    int tid = threadIdx.x;
    int i = blockIdx.x * 256 + tid;
    int v = (i < N) ? deg[i] : 0;
    s[tid] = v;
    __syncthreads();
    for (int off = 1; off < 256; off <<= 1) {
        int t = (tid >= off) ? s[tid - off] : 0;
        __syncthreads();
        s[tid] += t;
        __syncthreads();
    }
    if (i < N) tmp[i] = s[tid];
    if (tid == 255) bsum[blockIdx.x] = s[255];
}
__global__ void k_scan2(const int* __restrict__ bsum, int* __restrict__ boff, int nb) {
    __shared__ int s[1024];
    int tid = threadIdx.x;
    int v = (tid < nb) ? bsum[tid] : 0;
    s[tid] = v;
    __syncthreads();
    for (int off = 1; off < 1024; off <<= 1) {
        int t = (tid >= off) ? s[tid - off] : 0;
        __syncthreads();
        s[tid] += t;
        __syncthreads();
    }
    if (tid < nb) boff[tid] = s[tid] - v;   // exclusive
}
__global__ void k_scan3(const int* __restrict__ tmp, const int* __restrict__ boff,
                        int* __restrict__ row_ptr, int N) {
    int i = blockIdx.x * blockDim.x + threadIdx.x;
    if (i == 0) row_ptr[0] = 0;
    if (i < N) row_ptr[i + 1] = tmp[i] + boff[i >> 8];
}

// ---------------- CSR scatter; stores src, dst, eid per csr slot ----------------
__global__ void k_csr(const int* __restrict__ src, const int* __restrict__ dst,
                      const int* __restrict__ row_ptr, int* __restrict__ cursor,
                      int* __restrict__ csr_src, int* __restrict__ csr_dst,
                      int* __restrict__ csr_eid, int E, int N) {
    int e = blockIdx.x * blockDim.x + threadIdx.x;
    if (e >= E) return;
    int d = clampi(dst[e], N);
    int pos = row_ptr[d] + atomicAdd(&cursor[d], 1);
    if (pos < E) {
        csr_src[pos] = clampi(src[e], N);
        csr_dst[pos] = d;
        csr_eid[pos] = e;
    }
}

// ---------------- graph node counts — LDS histogram ----------------
#define MAXB 2048
__global__ void k_gse(const int* __restrict__ batch, int* __restrict__ gcnt, int N, int B) {
    __shared__ int s_cnt[MAXB];
    int t = threadIdx.x;
    int Bc = B < MAXB ? B : MAXB;
    for (int i = t; i < Bc; i += blockDim.x) s_cnt[i] = 0;
    __syncthreads();
    int n = blockIdx.x * blockDim.x + t;
    if (n < N) {
        int b = clampi(batch[n], B);
        if (b < MAXB) atomicAdd(&s_cnt[b], 1);
        else atomicAdd(&gcnt[b], 1);
    }
    __syncthreads();
    for (int i = t; i < Bc; i += blockDim.x)
        if (s_cnt[i] != 0) atomicAdd(&gcnt[i], s_cnt[i]);
}

// ---------------- ONCE: a_ed for all 3 layers x 4 heads, CSR order, 4 edges/thread ----
__global__ __launch_bounds__(256) void k_ee(
    const float* __restrict__ edge_attr, const float* __restrict__ eW,
    const float* __restrict__ eB, const float* __restrict__ lin_eW,
    const float* __restrict__ att_e, const int* __restrict__ csr_eid,
    float* __restrict__ aed, int E) {
    __shared__ float s_ew[256];    // [k*64+d]
    __shared__ float s_eb[64];
    __shared__ float s_wred[768];  // [l*256 + h*64 + d]
    int t = threadIdx.x;
    s_ew[t] = eW[t];
    if (t < 64) s_eb[t] = eB[t];
    for (int idx = t; idx < 768; idx += 256) {
        int l = idx >> 8, hd = idx & 255, hh = hd >> 6, d = hd & 63;
        const float* We = lin_eW + (size_t)l * HD * 256;
        const float* ae = att_e + (size_t)l * 256;
        float acc = 0.f;
        for (int c = 0; c < 64; c++)
            acc = fmaf(We[d * 256 + hh * 64 + c], ae[hh * 64 + c], acc);
        s_wred[idx] = acc;
    }
    __syncthreads();
    int j0 = (blockIdx.x * 256 + t) * 4;
    if (j0 >= E) return;
    float4 a[4];
    int nv = 0;
    #pragma unroll
    for (int q = 0; q < 4; q++) {
        int j = j0 + q;
        if (j < E) {
            a[q] = *(const float4*)(edge_attr + (size_t)csr_eid[j] * 4);
            nv = q + 1;
        } else {
            a[q] = make_float4(0.f, 0.f, 0.f, 0.f);
        }
    }
    float acc[4][12];
    #pragma unroll
    for (int q = 0; q < 4; q++)
        #pragma unroll
        for (int m = 0; m < 12; m++) acc[q][m] = 0.f;
    for (int k = 0; k < HD; k++) {
        float e0 = s_ew[k], e1 = s_ew[64 + k], e2 = s_ew[128 + k], e3 = s_ew[192 + k];
        float eb = s_eb[k];
        float w[12];
        #pragma unroll
        for (int m = 0; m < 12; m++)
            w[m] = s_wred[(m >> 2) * 256 + (m & 3) * 64 + k];
        #pragma unroll
        for (int q = 0; q < 4; q++) {
            float v = fmaf(a[q].x, e0, fmaf(a[q].y, e1,
                      fmaf(a[q].z, e2, fmaf(a[q].w, e3, eb))));
            v = fmaxf(v, 0.f);
            #pragma unroll
            for (int m = 0; m < 12; m++) acc[q][m] = fmaf(v, w[m], acc[q][m]);
        }
    }
    #pragma unroll
    for (int q = 0; q < 4; q++) {
        if (q >= nv) break;
        float* o = aed + (size_t)(j0 + q) * 12;
        #pragma unroll
        for (int m = 0; m < 12; m++) o[m] = acc[q][m];
    }
}

// ---------------- ONCE: self-loop a_ed rows by LINEARITY ----------------
__global__ void k_selfed(const int* __restrict__ row_ptr, float* __restrict__ aed,
                         int E, int N) {
    int n = blockIdx.x * blockDim.x + threadIdx.x;
    if (n >= N) return;
    int r0 = row_ptr[n], r1 = row_ptr[n + 1];
    float acc[12];
    #pragma unroll
    for (int m = 0; m < 12; m++) acc[m] = 0.f;
    for (int j = r0; j < r1; j++) {
        const float* p = aed + (size_t)j * 12;
        #pragma unroll
        for (int m = 0; m < 12; m++) acc[m] += p[m];
    }
    float inv = 1.f / fmaxf((float)(r1 - r0), 1.f);
    float* o = aed + (size_t)(E + n) * 12;
    #pragma unroll
    for (int m = 0; m < 12; m++) o[m] = acc[m] * inv;
}

// ---------------- per-layer: xp = h@W, 8 nodes per block ----------------
__global__ __launch_bounds__(256) void k_xp(
    const float* __restrict__ h, const float* __restrict__ W,
    const float* __restrict__ asrc, const float* __restrict__ adst,
    u16* __restrict__ xp, float* __restrict__ a_s, float* __restrict__ a_d, int N) {
    __shared__ float hs[8 * HD];
    int n0 = blockIdx.x * 8;
    int t = threadIdx.x;
    for (int i = t; i < 8 * HD; i += 256) {
        int nn = n0 + (i >> 6);
        hs[i] = (nn < N) ? h[(size_t)nn * HD + (i & 63)] : 0.f;
    }
    __syncthreads();
    int c = t;
    float acc[8];
    #pragma unroll
    for (int k = 0; k < 8; k++) acc[k] = 0.f;
    for (int d = 0; d < HD; d++) {
        float wv = W[d * 256 + c];
        #pragma unroll
        for (int k = 0; k < 8; k++) acc[k] = fmaf(hs[k * HD + d], wv, acc[k]);
    }
    float as_ = asrc[c], ad_ = adst[c];
    int hh = c >> 6, cc = c & 63;
    #pragma unroll
    for (int k = 0; k < 8; k++) {
        int nn = n0 + k;
        float ps = acc[k] * as_;
        float pd = acc[k] * ad_;
        #pragma unroll
        for (int o = 32; o > 0; o >>= 1) {
            ps += __shfl_xor(ps, o);
            pd += __shfl_xor(pd, o);
        }
        if (nn < N) {
            xp[(size_t)nn * 256 + c] = f2bf(acc[k]);
            if (cc == 0) { a_s[nn * 4 + hh] = ps; a_d[nn * 4 + hh] = pd; }
        }
    }
}

// ---------------- per-layer: attention weights (lite) ----------------
__global__ void k_w(const int* __restrict__ csr_src, const int* __restrict__ csr_dst,
                    const float* __restrict__ aed, const float* __restrict__ a_s,
                    const float* __restrict__ a_d, float* __restrict__ wcsr,
                    int layer, int E, int N) {
    int j = blockIdx.x * blockDim.x + threadIdx.x;
    if (j >= E + N) return;
    int s, d;
    if (j < E) { s = csr_src[j]; d = csr_dst[j]; }
    else       { s = j - E; d = s; }
    const float* p = aed + (size_t)j * 12 + layer * 4;
    float4 as4 = *(const float4*)(a_s + s * 4);
    float4 ad4 = *(const float4*)(a_d + d * 4);
    float w0 = __expf(lrelu(as4.x + ad4.x + p[0]));
    float w1 = __expf(lrelu(as4.y + ad4.y + p[1]));
    float w2 = __expf(lrelu(as4.z + ad4.z + p[2]));
    float w3 = __expf(lrelu(as4.w + ad4.w + p[3]));
    *(float4*)(wcsr + (size_t)j * 4) = make_float4(w0, w1, w2, w3);
}

// ---------------- per-layer GAT aggregate: edge-parallel within wave ----------------
__global__ __launch_bounds__(256) void k_gat(
    const u16* __restrict__ xp, const float* __restrict__ wcsr,
    const int* __restrict__ row_ptr, const int* __restrict__ csr_src,
    const float* __restrict__ convb, float* __restrict__ h_out, int N, int E) {
    int wave = threadIdx.x >> 6, lane = threadIdx.x & 63;
    int n = blockIdx.x * 4 + wave;
    if (n >= N) return;
    int g = lane >> 4, p = lane & 15;
    int r0 = row_ptr[n], r1 = row_ptr[n + 1];
    float a00 = 0.f, a01 = 0.f, a02 = 0.f, a03 = 0.f;
    float a10 = 0.f, a11 = 0.f, a12 = 0.f, a13 = 0.f;
    float a20 = 0.f, a21 = 0.f, a22 = 0.f, a23 = 0.f;
    float a30 = 0.f, a31 = 0.f, a32 = 0.f, a33 = 0.f;
    float d0 = 0.f, d1 = 0.f, d2 = 0.f, d3 = 0.f;
    if (g == 0) {
        float4 w = *(const float4*)(wcsr + (size_t)(E + n) * 4);
        const u16* row = xp + (size_t)n * 256 + p * 4;
        ushort4 v0 = *(const ushort4*)(row);
        ushort4 v1 = *(const ushort4*)(row + 64);
        ushort4 v2 = *(const ushort4*)(row + 128);
        ushort4 v3 = *(const ushort4*)(row + 192);
        d0 += w.x; d1 += w.y; d2 += w.z; d3 += w.w;
        a00 = fmaf(w.x, bf2f(v0.x), a00); a01 = fmaf(w.x, bf2f(v0.y), a01);
        a02 = fmaf(w.x, bf2f(v0.z), a02); a03 = fmaf(w.x, bf2f(v0.w), a03);
        a10 = fmaf(w.y, bf2f(v1.x), a10); a11 = fmaf(w.y, bf2f(v1.y), a11);
        a12 = fmaf(w.y, bf2f(v1.z), a12); a13 = fmaf(w.y, bf2f(v1.w), a13);
        a20 = fmaf(w.z, bf2f(v2.x), a20); a21 = fmaf(w.z, bf2f(v2.y), a21);
        a22 = fmaf(w.z, bf2f(v2.z), a22); a23 = fmaf(w.z, bf2f(v2.w), a23);
        a30 = fmaf(w.w, bf2f(v3.x), a30); a31 = fmaf(w.w, bf2f(v3.y), a31);
        a32 = fmaf(w.w, bf2f(v3.z), a32); a33 = fmaf(w.w, bf2f(v3.w), a33);
    }
    for (int j = r0 + g; j < r1; j += 4) {
        float4 w = *(const float4*)(wcsr + (size_t)j * 4);
        const u16* row = xp + (size_t)csr_src[j] * 256 + p * 4;
        ushort4 v0 = *(const ushort4*)(row);
        ushort4 v1 = *(const ushort4*)(row + 64);
        ushort4 v2 = *(const ushort4*)(row + 128);
        ushort4 v3 = *(const ushort4*)(row + 192);
        d0 += w.x; d1 += w.y; d2 += w.z; d3 += w.w;
        a00 = fmaf(w.x, bf2f(v0.x), a00); a01 = fmaf(w.x, bf2f(v0.y), a01);
        a02 = fmaf(w.x, bf2f(v0.z), a02); a03 = fmaf(w.x, bf2f(v0.w), a03);
        a10 = fmaf(w.y, bf2f(v1.x), a10); a11 = fmaf(w.y, bf2f(v1.y), a11);
        a12 = fmaf(w.y, bf2f(v1.z), a12); a13 = fmaf(w.y, bf2f(v1.w), a13);
        a20 = fmaf(w.z, bf2f(v2.x), a20); a21 = fmaf(w.z, bf2f(v2.y), a21);
        a22 = fmaf(w.z, bf2f(v2.z), a22); a23 = fmaf(w.z, bf2f(v2.w), a23);
        a30 = fmaf(w.w, bf2f(v3.x), a30); a31 = fmaf(w.w, bf2f(v3.y), a31);
        a32 = fmaf(w.w, bf2f(v3.z), a32); a33 = fmaf(w.w, bf2f(v3.w), a33);
    }
    d0 += __shfl_xor(d0, 16); d0 += __shfl_xor(d0, 32);
    d1 += __shfl_xor(d1, 16); d1 += __shfl_xor(d1, 32);
    d2 += __shfl_xor(d2, 16); d2 += __shfl_xor(d2, 32);
    d3 += __shfl_xor(d3, 16); d3 += __shfl_xor(d3, 32);
    float i0 = 1.f / d0, i1 = 1.f / d1, i2 = 1.f / d2, i3 = 1.f / d3;
    float m0 = a00 * i0 + a10 * i1 + a20 * i2 + a30 * i3;
    float m1 = a01 * i0 + a11 * i1 + a21 * i2 + a31 * i3;
    float m2 = a02 * i0 + a12 * i1 + a22 * i2 + a32 * i3;
    float m3 = a03 * i0 + a13 * i1 + a23 * i2 + a33 * i3;
    m0 += __shfl_xor(m0, 16); m0 += __shfl_xor(m0, 32);
    m1 += __shfl_xor(m1, 16); m1 += __shfl_xor(m1, 32);
    m2 += __shfl_xor(m2, 16); m2 += __shfl_xor(m2, 32);
    m3 += __shfl_xor(m3, 16); m3 += __shfl_xor(m3, 32);
    if (lane < 16) {
        int c = p * 4;
        h_out[(size_t)n * HD + c + 0] = fmaxf(0.25f * m0 + convb[c + 0], 0.f);
        h_out[(size_t)n * HD + c + 1] = fmaxf(0.25f * m1 + convb[c + 1], 0.f);
        h_out[(size_t)n * HD + c + 2] = fmaxf(0.25f * m2 + convb[c + 2], 0.f);
        h_out[(size_t)n * HD + c + 3] = fmaxf(0.25f * m3 + convb[c + 3], 0.f);
    }
}

// ---------------- global pool, node-parallel with atomics ----------------
__global__ void k_pool(const float* __restrict__ h, const int* __restrict__ batch,
                       float* __restrict__ pooled, int N, int B) {
    int i = blockIdx.x * blockDim.x + threadIdx.x;
    if (i >= N * HD) return;
    int n = i >> 6, c = i & 63;
    int b = clampi(batch[n], B);
    atomicAdd(&pooled[b * HD + c], h[i]);
}

// ---------------- final MLP (fp32 out; divides pooled sum by count) ----------------
__global__ void k_mlp(const float* __restrict__ u, const float* __restrict__ gW,
                      const float* __restrict__ gb, const float* __restrict__ pooled,
                      const int* __restrict__ gcnt, const float* __restrict__ f1W,
                      const float* __restrict__ f1b, const float* __restrict__ f2W,
                      const float* __restrict__ f2b, float* __restrict__ out, int B) {
    __shared__ float z[2 * HD];
    __shared__ float z1s[HD];
    int b = blockIdx.x, t = threadIdx.x;  // 64 threads
    float acc = gb[t];
    for (int k = 0; k < 10; k++) acc = fmaf(u[b * 10 + k], gW[k * HD + t], acc);
    z[HD + t] = fmaxf(acc, 0.f);
    float invc = 1.f / fmaxf((float)gcnt[b], 1.f);
    z[t] = pooled[b * HD + t] * invc;
    __syncthreads();
    float a1 = f1b[t];
    for (int k = 0; k < 2 * HD; k++) a1 = fmaf(z[k], f1W[k * HD + t], a1);
    z1s[t] = fmaxf(a1, 0.f);
    __syncthreads();
    if (t < 2) {
        float o = f2b[t];
        for (int k = 0; k < HD; k++) o = fmaf(z1s[k], f2W[k * 2 + t], o);
        out[b * 2 + t] = o;
    }
}

extern "C" void kernel_launch(void* const* d_in, const int* in_sizes, int n_in,
                              void* d_out, int out_size, void* d_ws, size_t ws_size,
                              hipStream_t stream) {
    const float* x         = (const float*)d_in[0];
    const int*   ei        = (const int*)d_in[1];
    const float* edge_attr = (const float*)d_in[2];
    const float* u         = (const float*)d_in[3];
    const int*   batch     = (const int*)d_in[4];
    const float* node_W    = (const float*)d_in[5];
    const float* node_b    = (const float*)d_in[6];
    const float* eemb_W    = (const float*)d_in[7];
    const float* eemb_b    = (const float*)d_in[8];
    const float* lin_W     = (const float*)d_in[9];
    const float* att_src   = (const float*)d_in[10];
    const float* att_dst   = (const float*)d_in[11];
    const float* lin_eW    = (const float*)d_in[12];
    const float* att_e     = (const float*)d_in[13];
    const float* conv_b    = (const float*)d_in[14];
    const float* gW        = (const float*)d_in[15];
    const float* gb        = (const float*)d_in[16];
    const float* f1W       = (const float*)d_in[17];
    const float* f1b       = (const float*)d_in[18];
    const float* f2W       = (const float*)d_in[19];
    const float* f2b       = (const float*)d_in[20];

    const int N = in_sizes[0] / 3;
    const int E = in_sizes[2] / 4;
    const int B = in_sizes[3] / 10;
    const int* src = ei;
    const int* dst = ei + E;
    const int NB = (N + 255) / 256;   // scan blocks

    // workspace carve (fp32 then bf16 then ints)
    float* wsf = (float*)d_ws;
    float* h       = wsf;              wsf += (size_t)N * HD;
    float* a_s     = wsf;              wsf += (size_t)N * 4;
    float* a_d     = wsf;              wsf += (size_t)N * 4;
    float* aed     = wsf;              wsf += (size_t)(E + N) * 12;
    float* wcsr    = wsf;              wsf += (size_t)(E + N) * 4;
    float* pooled  = wsf;              wsf += (size_t)B * HD;
    u16* xp = (u16*)wsf;               wsf += (size_t)N * 128;   // N*256 bf16
    int* wsi = (int*)wsf;
    int* deg     = wsi;                wsi += N;
    int* row_ptr = wsi;                wsi += N + 1;
    int* cursor  = wsi;                wsi += N;
    int* tmp     = wsi;                wsi += N;
    int* bsum    = wsi;                wsi += NB + 1;
    int* boff    = wsi;                wsi += NB + 1;
    int* csr_src = wsi;                wsi += E;
    int* csr_dst = wsi;                wsi += E;
    int* csr_eid = wsi;                wsi += E;
    int* gcnt    = wsi;                wsi += B;

    k_init<<<NB, 256, 0, stream>>>(deg, cursor, gcnt, pooled, N, B);
    k_node_emb<<<(N * HD + 255) / 256, 256, 0, stream>>>(x, node_W, node_b, h, N);
    k_deg<<<(E + 255) / 256, 256, 0, stream>>>(dst, deg, E, N);
    k_scan1<<<NB, 256, 0, stream>>>(deg, tmp, bsum, N);
    k_scan2<<<1, 1024, 0, stream>>>(bsum, boff, NB);
    k_scan3<<<NB, 256, 0, stream>>>(tmp, boff, row_ptr, N);
    k_csr<<<(E + 255) / 256, 256, 0, stream>>>(src, dst, row_ptr, cursor,
                                               csr_src, csr_dst, csr_eid, E, N);
    k_gse<<<NB, 256, 0, stream>>>(batch, gcnt, N, B);
    k_ee<<<(E + 1023) / 1024, 256, 0, stream>>>(edge_attr, eemb_W, eemb_b, lin_eW, att_e,
                                                csr_eid, aed, E);
    k_selfed<<<NB, 256, 0, stream>>>(row_ptr, aed, E, N);
    for (int i = 0; i < 3; i++) {
        k_xp<<<(N + 7) / 8, 256, 0, stream>>>(h, lin_W + (size_t)i * HD * 256,
                                              att_src + (size_t)i * 256,
                                              att_dst + (size_t)i * 256,
                                              xp, a_s, a_d, N);
        k_w<<<(E + N + 255) / 256, 256, 0, stream>>>(csr_src, csr_dst, aed, a_s, a_d,
                                                     wcsr, i, E, N);
        k_gat<<<(N + 3) / 4, 256, 0, stream>>>(xp, wcsr, row_ptr, csr_src,
                                               conv_b + (size_t)i * HD, h, N, E);
    }
    k_pool<<<(N * HD + 255) / 256, 256, 0, stream>>>(h, batch, pooled, N, B);
    k_mlp<<<B, 64, 0, stream>>>(u, gW, gb, pooled, gcnt, f1W, f1b, f2W, f2b,
                                (float*)d_out, B);
}